// Round 5
// baseline (249.440 us; speedup 1.0000x reference)
//
#include <hip/hip_runtime.h>

#define NODES 10000
#define BATCH 8
#define CH    128
#define KNB   16
#define CO    256

typedef __bf16 bf16x8 __attribute__((ext_vector_type(8)));
typedef float  f32x4  __attribute__((ext_vector_type(4)));

__device__ __forceinline__ unsigned short f2bf(float f) {
  unsigned u = __float_as_uint(f);
  u = (u + 0x7FFFu + ((u >> 16) & 1u)) >> 16;   // RNE
  return (unsigned short)u;
}
__device__ __forceinline__ unsigned pk2(float a, float b) {
  return (unsigned)f2bf(a) | ((unsigned)f2bf(b) << 16);
}
// max of packed non-negative bf16 == packed u16 max (relu guarantees >=0)
__device__ __forceinline__ unsigned pkmax(unsigned a, unsigned b) {
  unsigned d;
  asm("v_pk_max_u16 %0, %1, %2" : "=v"(d) : "v"(a), "v"(b));
  return d;
}
__device__ __forceinline__ uint4 pkmax4(uint4 a, uint4 b) {
  a.x = pkmax(a.x, b.x); a.y = pkmax(a.y, b.y);
  a.z = pkmax(a.z, b.z); a.w = pkmax(a.w, b.w);
  return a;
}
__device__ __forceinline__ bf16x8 asbf8(uint4 u) {
  union { uint4 u; bf16x8 b; } c; c.u = u; return c.b;
}

// ---------------------------------------------------------------------------
// fp32 -> bf16 weight conversion (row-major [d][k] kept)
// ---------------------------------------------------------------------------
__global__ __launch_bounds__(256) void prep(
    const float* __restrict__ W1, const float* __restrict__ Wp,
    const float* __restrict__ W2,
    unsigned short* __restrict__ W1b, unsigned short* __restrict__ Wpb,
    unsigned short* __restrict__ W2b)
{
  int i = blockIdx.x * 256 + threadIdx.x;   // float4 index, 24576 total
  const float* src; unsigned short* dst; int off;
  if (i < 4096)      { src = W1; dst = W1b; off = i; }
  else if (i < 8192) { src = Wp; dst = Wpb; off = i - 4096; }
  else               { src = W2; dst = W2b; off = i - 8192; }
  float4 v = ((const float4*)src)[off];
  ushort4 o;
  o.x = f2bf(v.x); o.y = f2bf(v.y); o.z = f2bf(v.z); o.w = f2bf(v.w);
  ((ushort4*)dst)[off] = o;
}

// ---------------------------------------------------------------------------
// Fused h = relu(W1 x + b1), z = relu(Wp h + bp), both bf16 [b][n][128].
// Wave-independent, 32 nodes/wave (2 MFMA n-tiles), no __syncthreads.
// x B-fragments loaded straight to registers; h round-trips D->B layout
// through a wave-private 8KB LDS slice (intra-wave waitcnt only).
// A (W1/Wp) streamed from L2 with depth-2 rotating prefetch.
// ---------------------------------------------------------------------------
__global__ __launch_bounds__(256) void fused_hz(
    const unsigned short* __restrict__ W1b, const float* __restrict__ b1,
    const unsigned short* __restrict__ Wpb, const float* __restrict__ bp,
    const float* __restrict__ x,
    unsigned short* __restrict__ h_t, unsigned short* __restrict__ z_t)
{
  const int b    = blockIdx.y;
  const int t    = threadIdx.x;
  const int w    = t >> 6, lane = t & 63;
  const int lm   = lane & 15, q = lane >> 4;
  const int nw0  = blockIdx.x * 128 + w * 32;

  __shared__ __align__(16) unsigned short Hs_all[4][32 * 128];  // 8KB/wave
  char* Hs = (char*)Hs_all[w];

  int node[2], gn[2];
  node[0] = nw0 + lm;      gn[0] = node[0] < NODES ? node[0] : NODES - 1;
  node[1] = nw0 + 16 + lm; gn[1] = node[1] < NODES ? node[1] : NODES - 1;

  // ---- x B-fragments to registers: x[c][gn], c = kt*32 + q*8 + j
  uint4 B1[2][4];
#pragma unroll
  for (int nt = 0; nt < 2; ++nt) {
    const float* X = x + (size_t)b * CH * NODES + gn[nt];
    float xv[32];
#pragma unroll
    for (int kt = 0; kt < 4; ++kt)
#pragma unroll
      for (int j = 0; j < 8; ++j)
        xv[kt * 8 + j] = X[(size_t)(kt * 32 + q * 8 + j) * NODES];
#pragma unroll
    for (int kt = 0; kt < 4; ++kt) {
      B1[nt][kt].x = pk2(xv[kt * 8 + 0], xv[kt * 8 + 1]);
      B1[nt][kt].y = pk2(xv[kt * 8 + 2], xv[kt * 8 + 3]);
      B1[nt][kt].z = pk2(xv[kt * 8 + 4], xv[kt * 8 + 5]);
      B1[nt][kt].w = pk2(xv[kt * 8 + 6], xv[kt * 8 + 7]);
    }
  }

  // ---- phase 1: h = relu(W1 x + b1), depth-2 A prefetch
  uint4 a[2][4];
#pragma unroll
  for (int kt = 0; kt < 4; ++kt) {
    a[0][kt] = *(const uint4*)(W1b + (size_t)(0 * 16 + lm) * CH + kt * 32 + q * 8);
    a[1][kt] = *(const uint4*)(W1b + (size_t)(1 * 16 + lm) * CH + kt * 32 + q * 8);
  }
#pragma unroll
  for (int dt = 0; dt < 8; ++dt) {
    f32x4 acc0 = (f32x4){0.f, 0.f, 0.f, 0.f};
    f32x4 acc1 = (f32x4){0.f, 0.f, 0.f, 0.f};
#pragma unroll
    for (int kt = 0; kt < 4; ++kt) {
      acc0 = __builtin_amdgcn_mfma_f32_16x16x32_bf16(
          asbf8(a[dt & 1][kt]), asbf8(B1[0][kt]), acc0, 0, 0, 0);
      acc1 = __builtin_amdgcn_mfma_f32_16x16x32_bf16(
          asbf8(a[dt & 1][kt]), asbf8(B1[1][kt]), acc1, 0, 0, 0);
    }
    if (dt < 6) {
#pragma unroll
      for (int kt = 0; kt < 4; ++kt)
        a[dt & 1][kt] = *(const uint4*)(W1b + (size_t)((dt + 2) * 16 + lm) * CH
                                        + kt * 32 + q * 8);
    }
    const int d0 = dt * 16 + q * 4;
    float4 bi = *(const float4*)(b1 + d0);
    f32x4 aa[2] = {acc0, acc1};
#pragma unroll
    for (int nt = 0; nt < 2; ++nt) {
      ushort4 o;
      o.x = f2bf(fmaxf(aa[nt][0] + bi.x, 0.f));
      o.y = f2bf(fmaxf(aa[nt][1] + bi.y, 0.f));
      o.z = f2bf(fmaxf(aa[nt][2] + bi.z, 0.f));
      o.w = f2bf(fmaxf(aa[nt][3] + bi.w, 0.f));
      if (node[nt] < NODES)
        *(ushort4*)(h_t + ((size_t)b * NODES + node[nt]) * CH + d0) = o;
      const int row = nt * 16 + lm;
      const int chunk = dt * 2 + (q >> 1);
      *(ushort4*)(Hs + row * 256 + ((chunk ^ (row & 7)) << 4) + ((q & 1) << 3)) = o;
    }
  }

  // ---- h D-layout -> B-fragments (same wave, waitcnt only)
  uint4 B2[2][4];
#pragma unroll
  for (int nt = 0; nt < 2; ++nt) {
    const int row = nt * 16 + lm;
#pragma unroll
    for (int kt = 0; kt < 4; ++kt)
      B2[nt][kt] = *(const uint4*)(Hs + row * 256 + (((kt * 4 + q) ^ (row & 7)) << 4));
  }

  // ---- phase 2: z = relu(Wp h + bp)
#pragma unroll
  for (int kt = 0; kt < 4; ++kt) {
    a[0][kt] = *(const uint4*)(Wpb + (size_t)(0 * 16 + lm) * CH + kt * 32 + q * 8);
    a[1][kt] = *(const uint4*)(Wpb + (size_t)(1 * 16 + lm) * CH + kt * 32 + q * 8);
  }
#pragma unroll
  for (int dt = 0; dt < 8; ++dt) {
    f32x4 acc0 = (f32x4){0.f, 0.f, 0.f, 0.f};
    f32x4 acc1 = (f32x4){0.f, 0.f, 0.f, 0.f};
#pragma unroll
    for (int kt = 0; kt < 4; ++kt) {
      acc0 = __builtin_amdgcn_mfma_f32_16x16x32_bf16(
          asbf8(a[dt & 1][kt]), asbf8(B2[0][kt]), acc0, 0, 0, 0);
      acc1 = __builtin_amdgcn_mfma_f32_16x16x32_bf16(
          asbf8(a[dt & 1][kt]), asbf8(B2[1][kt]), acc1, 0, 0, 0);
    }
    if (dt < 6) {
#pragma unroll
      for (int kt = 0; kt < 4; ++kt)
        a[dt & 1][kt] = *(const uint4*)(Wpb + (size_t)((dt + 2) * 16 + lm) * CH
                                        + kt * 32 + q * 8);
    }
    const int d0 = dt * 16 + q * 4;
    float4 bi = *(const float4*)(bp + d0);
    f32x4 aa[2] = {acc0, acc1};
#pragma unroll
    for (int nt = 0; nt < 2; ++nt) {
      if (node[nt] < NODES) {
        ushort4 o;
        o.x = f2bf(fmaxf(aa[nt][0] + bi.x, 0.f));
        o.y = f2bf(fmaxf(aa[nt][1] + bi.y, 0.f));
        o.z = f2bf(fmaxf(aa[nt][2] + bi.z, 0.f));
        o.w = f2bf(fmaxf(aa[nt][3] + bi.w, 0.f));
        *(ushort4*)(z_t + ((size_t)b * NODES + node[nt]) * CH + d0) = o;
      }
    }
  }
}

// ---------------------------------------------------------------------------
// out[b][d][n] = relu(W2 @ [h[n]; max_k z[idx[n,k]]] + b2), d=256, K=256.
// ZERO LDS, ZERO BARRIERS: lane (lm,q)'s B-fragment chunk pattern (kt*4+q)
// IS the quad-coalesced 64B gather pattern, so h-load and pkmax gather-max
// accumulate directly into the 8 B-fragment VGPRs. 256-thr blocks, 4
// independent waves, 32 nodes/wave. W2 A-stream: 3-buffer rotating prefetch
// (~2.5 steps ahead ~ L2 latency). b = bid&7 -> per-XCD batch affinity.
// ---------------------------------------------------------------------------
__global__ __launch_bounds__(256) void out_kernel(
    const unsigned short* __restrict__ h_t, const unsigned short* __restrict__ z_t,
    const int* __restrict__ e0, const unsigned short* __restrict__ W2b,
    const float* __restrict__ b2, float* __restrict__ out)
{
  const int bid = blockIdx.x;
  const int b   = bid & 7;
  const int t   = threadIdx.x;
  const int w   = t >> 6, lane = t & 63;
  const int lm  = lane & 15, q = lane >> 4;
  const int nw0 = (bid >> 3) * 128 + w * 32;

  int node[2], gn[2];
  node[0] = nw0 + lm;      gn[0] = node[0] < NODES ? node[0] : NODES - 1;
  node[1] = nw0 + 16 + lm; gn[1] = node[1] < NODES ? node[1] : NODES - 1;

  // ---- neighbor indices (all 16 per node; redundant across q, L1-served)
  uint4 iv[2][4];
#pragma unroll
  for (int nt = 0; nt < 2; ++nt)
#pragma unroll
    for (int jq = 0; jq < 4; ++jq)
      iv[nt][jq] = *(const uint4*)(e0 + ((size_t)b * NODES + gn[nt]) * KNB + jq * 4);

  // ---- h -> Bf[nt][0..3] directly (chunk kt*4+q of node row)
  uint4 Bf[2][8];
#pragma unroll
  for (int nt = 0; nt < 2; ++nt)
#pragma unroll
    for (int kt = 0; kt < 4; ++kt)
      Bf[nt][kt] = *(const uint4*)(h_t + ((size_t)b * NODES + gn[nt]) * CH
                                   + (kt * 4 + q) * 8);

  // ---- gather-max -> Bf[nt][4..7] directly (z chunk j*4+q, 64B/quad)
  const unsigned short* Zb = z_t + (size_t)b * NODES * CH;
#pragma unroll
  for (int nt = 0; nt < 2; ++nt) {
    unsigned jns[KNB];
#pragma unroll
    for (int jq = 0; jq < 4; ++jq) {
      jns[jq * 4 + 0] = iv[nt][jq].x; jns[jq * 4 + 1] = iv[nt][jq].y;
      jns[jq * 4 + 2] = iv[nt][jq].z; jns[jq * 4 + 3] = iv[nt][jq].w;
    }
    uint4 m[4];
#pragma unroll
    for (int j = 0; j < 4; ++j) m[j] = make_uint4(0u, 0u, 0u, 0u);
#pragma unroll
    for (int k = 0; k < KNB; ++k) {
      const unsigned short* pz = Zb + (size_t)jns[k] * CH + q * 8;
#pragma unroll
      for (int j = 0; j < 4; ++j)
        m[j] = pkmax4(m[j], *(const uint4*)(pz + j * 32));
    }
#pragma unroll
    for (int j = 0; j < 4; ++j) Bf[nt][4 + j] = m[j];
  }

  // ---- sweep 256 output channels: s = dt*2 + half, 3-buffer A prefetch
  uint4 A[3][4];
#pragma unroll
  for (int s = 0; s < 3; ++s)
#pragma unroll
    for (int kt = 0; kt < 4; ++kt)
      A[s][kt] = *(const uint4*)(W2b + (size_t)((s >> 1) * 16 + lm) * CO
                                 + ((s & 1) * 4 + kt) * 32 + q * 8);

  f32x4 acc0 = (f32x4){0.f, 0.f, 0.f, 0.f};
  f32x4 acc1 = (f32x4){0.f, 0.f, 0.f, 0.f};

#pragma unroll
  for (int s = 0; s < 32; ++s) {
    const int dt = s >> 1, half = s & 1, slot = s % 3;
#pragma unroll
    for (int kt = 0; kt < 4; ++kt) {
      const int ktg = half * 4 + kt;
      acc0 = __builtin_amdgcn_mfma_f32_16x16x32_bf16(
          asbf8(A[slot][kt]), asbf8(Bf[0][ktg]), acc0, 0, 0, 0);
      acc1 = __builtin_amdgcn_mfma_f32_16x16x32_bf16(
          asbf8(A[slot][kt]), asbf8(Bf[1][ktg]), acc1, 0, 0, 0);
    }
    if (s + 3 < 32) {
      const int sn = s + 3, dn = sn >> 1, hn = sn & 1;
#pragma unroll
      for (int kt = 0; kt < 4; ++kt)
        A[slot][kt] = *(const uint4*)(W2b + (size_t)(dn * 16 + lm) * CO
                                      + (hn * 4 + kt) * 32 + q * 8);
    }
    if (half == 1) {
      const int d0 = dt * 16 + q * 4;
      float4 bi = *(const float4*)(b2 + d0);
      float bv[4] = {bi.x, bi.y, bi.z, bi.w};
      f32x4 aa[2] = {acc0, acc1};
#pragma unroll
      for (int nt = 0; nt < 2; ++nt) {
        if (node[nt] < NODES) {
          float* op = out + (size_t)(b * CO + d0) * NODES + node[nt];
#pragma unroll
          for (int r = 0; r < 4; ++r)
            op[(size_t)r * NODES] = fmaxf(aa[nt][r] + bv[r], 0.f);
        }
      }
      acc0 = (f32x4){0.f, 0.f, 0.f, 0.f};
      acc1 = (f32x4){0.f, 0.f, 0.f, 0.f};
    }
  }
}

// ---------------------------------------------------------------------------
extern "C" void kernel_launch(void* const* d_in, const int* in_sizes, int n_in,
                              void* d_out, int out_size, void* d_ws, size_t ws_size,
                              hipStream_t stream) {
  const float* x  = (const float*)d_in[0];
  const int*   ei = (const int*)d_in[1];   // (2,B,N,K); first half = targets
  const float* W1 = (const float*)d_in[2];
  const float* b1 = (const float*)d_in[3];
  const float* Wp = (const float*)d_in[4];
  const float* bp = (const float*)d_in[5];
  const float* W2 = (const float*)d_in[6];
  const float* b2 = (const float*)d_in[7];
  float* out = (float*)d_out;

  unsigned short* ws  = (unsigned short*)d_ws;
  unsigned short* h_t = ws;                                   // [B][N][128] bf16
  unsigned short* z_t = h_t + (size_t)BATCH * NODES * CH;     // [B][N][128] bf16
  unsigned short* W1b = z_t + (size_t)BATCH * NODES * CH;
  unsigned short* Wpb = W1b + CH * CH;
  unsigned short* W2b = Wpb + CH * CH;

  prep<<<96, 256, 0, stream>>>(W1, Wp, W2, W1b, Wpb, W2b);

  const int NT = (NODES + 127) / 128;   // 79
  fused_hz<<<dim3(NT, BATCH), 256, 0, stream>>>(W1b, b1, Wpb, bp, x, h_t, z_t);
  out_kernel<<<BATCH * NT, 256, 0, stream>>>(h_t, z_t, ei, W2b, b2, out);
}

// Round 6
// 205.317 us; speedup vs baseline: 1.2149x; 1.2149x over previous
//
#include <hip/hip_runtime.h>

#define NODES 10000
#define BATCH 8
#define CH    128
#define KNB   16
#define CO    256

typedef __bf16 bf16x8 __attribute__((ext_vector_type(8)));
typedef float  f32x4  __attribute__((ext_vector_type(4)));

__device__ __forceinline__ unsigned short f2bf(float f) {
  unsigned u = __float_as_uint(f);
  u = (u + 0x7FFFu + ((u >> 16) & 1u)) >> 16;   // RNE
  return (unsigned short)u;
}
__device__ __forceinline__ unsigned pk2(float a, float b) {
  return (unsigned)f2bf(a) | ((unsigned)f2bf(b) << 16);
}
// max of packed non-negative bf16 == packed u16 max (relu guarantees >=0)
__device__ __forceinline__ unsigned pkmax(unsigned a, unsigned b) {
  unsigned d;
  asm("v_pk_max_u16 %0, %1, %2" : "=v"(d) : "v"(a), "v"(b));
  return d;
}
__device__ __forceinline__ uint4 pkmax4(uint4 a, uint4 b) {
  a.x = pkmax(a.x, b.x); a.y = pkmax(a.y, b.y);
  a.z = pkmax(a.z, b.z); a.w = pkmax(a.w, b.w);
  return a;
}
__device__ __forceinline__ bf16x8 asbf8(uint4 u) {
  union { uint4 u; bf16x8 b; } c; c.u = u; return c.b;
}

// ---------------------------------------------------------------------------
// fp32 -> bf16 weight conversion (row-major [d][k] kept)
// ---------------------------------------------------------------------------
__global__ __launch_bounds__(256) void prep(
    const float* __restrict__ W1, const float* __restrict__ Wp,
    const float* __restrict__ W2,
    unsigned short* __restrict__ W1b, unsigned short* __restrict__ Wpb,
    unsigned short* __restrict__ W2b)
{
  int i = blockIdx.x * 256 + threadIdx.x;   // float4 index, 24576 total
  const float* src; unsigned short* dst; int off;
  if (i < 4096)      { src = W1; dst = W1b; off = i; }
  else if (i < 8192) { src = Wp; dst = Wpb; off = i - 4096; }
  else               { src = W2; dst = W2b; off = i - 8192; }
  float4 v = ((const float4*)src)[off];
  ushort4 o;
  o.x = f2bf(v.x); o.y = f2bf(v.y); o.z = f2bf(v.z); o.w = f2bf(v.w);
  ((ushort4*)dst)[off] = o;
}

// ---------------------------------------------------------------------------
// Fused h = relu(W1 x + b1), z = relu(Wp h + bp), both bf16 [b][n][128].
// Wave-independent (no __syncthreads), 32 nodes/wave. x B-fragments loaded
// straight to registers; D->B relayout via wave-private 8KB LDS; h and z
// leave through LDS as fully-contiguous 1KB/wave dwordx4 stores.
// ---------------------------------------------------------------------------
__global__ __launch_bounds__(256) void fused_hz(
    const unsigned short* __restrict__ W1b, const float* __restrict__ b1,
    const unsigned short* __restrict__ Wpb, const float* __restrict__ bp,
    const float* __restrict__ x,
    unsigned short* __restrict__ h_t, unsigned short* __restrict__ z_t)
{
  const int b    = blockIdx.y;
  const int t    = threadIdx.x;
  const int w    = t >> 6, lane = t & 63;
  const int lm   = lane & 15, q = lane >> 4;
  const int nw0  = blockIdx.x * 128 + w * 32;

  __shared__ __align__(16) unsigned short Hs_all[4][32 * 128];  // 8KB/wave
  char* Hs = (char*)Hs_all[w];

  int node[2], gn[2];
  node[0] = nw0 + lm;      gn[0] = node[0] < NODES ? node[0] : NODES - 1;
  node[1] = nw0 + 16 + lm; gn[1] = node[1] < NODES ? node[1] : NODES - 1;

  // ---- x B-fragments to registers: x[c][gn], c = kt*32 + q*8 + j
  uint4 B1[2][4];
#pragma unroll
  for (int nt = 0; nt < 2; ++nt) {
    const float* X = x + (size_t)b * CH * NODES + gn[nt];
    float xv[32];
#pragma unroll
    for (int kt = 0; kt < 4; ++kt)
#pragma unroll
      for (int j = 0; j < 8; ++j)
        xv[kt * 8 + j] = X[(size_t)(kt * 32 + q * 8 + j) * NODES];
#pragma unroll
    for (int kt = 0; kt < 4; ++kt) {
      B1[nt][kt].x = pk2(xv[kt * 8 + 0], xv[kt * 8 + 1]);
      B1[nt][kt].y = pk2(xv[kt * 8 + 2], xv[kt * 8 + 3]);
      B1[nt][kt].z = pk2(xv[kt * 8 + 4], xv[kt * 8 + 5]);
      B1[nt][kt].w = pk2(xv[kt * 8 + 6], xv[kt * 8 + 7]);
    }
  }

  // ---- phase 1: h = relu(W1 x + b1), depth-2 A prefetch, D-frags -> LDS
  uint4 a[2][4];
#pragma unroll
  for (int kt = 0; kt < 4; ++kt) {
    a[0][kt] = *(const uint4*)(W1b + (size_t)(lm) * CH + kt * 32 + q * 8);
    a[1][kt] = *(const uint4*)(W1b + (size_t)(16 + lm) * CH + kt * 32 + q * 8);
  }
#pragma unroll
  for (int dt = 0; dt < 8; ++dt) {
    f32x4 acc0 = (f32x4){0.f, 0.f, 0.f, 0.f};
    f32x4 acc1 = (f32x4){0.f, 0.f, 0.f, 0.f};
#pragma unroll
    for (int kt = 0; kt < 4; ++kt) {
      acc0 = __builtin_amdgcn_mfma_f32_16x16x32_bf16(
          asbf8(a[dt & 1][kt]), asbf8(B1[0][kt]), acc0, 0, 0, 0);
      acc1 = __builtin_amdgcn_mfma_f32_16x16x32_bf16(
          asbf8(a[dt & 1][kt]), asbf8(B1[1][kt]), acc1, 0, 0, 0);
    }
    if (dt < 6) {
#pragma unroll
      for (int kt = 0; kt < 4; ++kt)
        a[dt & 1][kt] = *(const uint4*)(W1b + (size_t)((dt + 2) * 16 + lm) * CH
                                        + kt * 32 + q * 8);
    }
    const int d0 = dt * 16 + q * 4;
    float4 bi = *(const float4*)(b1 + d0);
    f32x4 aa[2] = {acc0, acc1};
#pragma unroll
    for (int nt = 0; nt < 2; ++nt) {
      ushort4 o;
      o.x = f2bf(fmaxf(aa[nt][0] + bi.x, 0.f));
      o.y = f2bf(fmaxf(aa[nt][1] + bi.y, 0.f));
      o.z = f2bf(fmaxf(aa[nt][2] + bi.z, 0.f));
      o.w = f2bf(fmaxf(aa[nt][3] + bi.w, 0.f));
      const int row = nt * 16 + lm;
      const int chunk = dt * 2 + (q >> 1);
      *(ushort4*)(Hs + row * 256 + ((chunk ^ (row & 7)) << 4) + ((q & 1) << 3)) = o;
    }
  }

  // ---- h D-layout -> B-fragments (intra-wave, waitcnt only)
  uint4 B2[2][4];
#pragma unroll
  for (int nt = 0; nt < 2; ++nt) {
    const int row = nt * 16 + lm;
#pragma unroll
    for (int kt = 0; kt < 4; ++kt)
      B2[nt][kt] = *(const uint4*)(Hs + row * 256 + (((kt * 4 + q) ^ (row & 7)) << 4));
  }

  // ---- contiguous h store: lane (srow=lane>>4, schk=lane&15), 8 passes
  {
    const int srow = lane >> 4, schk = lane & 15;
#pragma unroll
    for (int p = 0; p < 8; ++p) {
      const int row = p * 4 + srow;
      const int gnode = nw0 + row;
      uint4 vv = *(const uint4*)(Hs + row * 256 + ((schk ^ (row & 7)) << 4));
      if (gnode < NODES)
        *(uint4*)(h_t + ((size_t)b * NODES + gnode) * CH + schk * 8) = vv;
    }
  }

  // ---- phase 2: z = relu(Wp h + bp), D-frags -> LDS (reuse Hs)
#pragma unroll
  for (int kt = 0; kt < 4; ++kt) {
    a[0][kt] = *(const uint4*)(Wpb + (size_t)(lm) * CH + kt * 32 + q * 8);
    a[1][kt] = *(const uint4*)(Wpb + (size_t)(16 + lm) * CH + kt * 32 + q * 8);
  }
#pragma unroll
  for (int dt = 0; dt < 8; ++dt) {
    f32x4 acc0 = (f32x4){0.f, 0.f, 0.f, 0.f};
    f32x4 acc1 = (f32x4){0.f, 0.f, 0.f, 0.f};
#pragma unroll
    for (int kt = 0; kt < 4; ++kt) {
      acc0 = __builtin_amdgcn_mfma_f32_16x16x32_bf16(
          asbf8(a[dt & 1][kt]), asbf8(B2[0][kt]), acc0, 0, 0, 0);
      acc1 = __builtin_amdgcn_mfma_f32_16x16x32_bf16(
          asbf8(a[dt & 1][kt]), asbf8(B2[1][kt]), acc1, 0, 0, 0);
    }
    if (dt < 6) {
#pragma unroll
      for (int kt = 0; kt < 4; ++kt)
        a[dt & 1][kt] = *(const uint4*)(Wpb + (size_t)((dt + 2) * 16 + lm) * CH
                                        + kt * 32 + q * 8);
    }
    const int d0 = dt * 16 + q * 4;
    float4 bi = *(const float4*)(bp + d0);
    f32x4 aa[2] = {acc0, acc1};
#pragma unroll
    for (int nt = 0; nt < 2; ++nt) {
      ushort4 o;
      o.x = f2bf(fmaxf(aa[nt][0] + bi.x, 0.f));
      o.y = f2bf(fmaxf(aa[nt][1] + bi.y, 0.f));
      o.z = f2bf(fmaxf(aa[nt][2] + bi.z, 0.f));
      o.w = f2bf(fmaxf(aa[nt][3] + bi.w, 0.f));
      const int row = nt * 16 + lm;
      const int chunk = dt * 2 + (q >> 1);
      *(ushort4*)(Hs + row * 256 + ((chunk ^ (row & 7)) << 4) + ((q & 1) << 3)) = o;
    }
  }

  // ---- contiguous z store
  {
    const int srow = lane >> 4, schk = lane & 15;
#pragma unroll
    for (int p = 0; p < 8; ++p) {
      const int row = p * 4 + srow;
      const int gnode = nw0 + row;
      uint4 vv = *(const uint4*)(Hs + row * 256 + ((schk ^ (row & 7)) << 4));
      if (gnode < NODES)
        *(uint4*)(z_t + ((size_t)b * NODES + gnode) * CH + schk * 8) = vv;
    }
  }
}

// ---------------------------------------------------------------------------
// out[b][d][n] = relu(W2 @ [h[n]; max_k z[idx[n,k]]] + b2), d=256, K=256.
// R3 tile structure (256 thr, 64 nodes, ONE barrier) with a deep-pipelined
// gather: thread = (node nl=t>>2, c=t&3); per 16B chunk, all 16 neighbor
// loads batched into v[16] (16 KB in flight per wave) then 15-op pkmax tree.
// Quad lanes c=0..3 cover contiguous 64B of the same neighbor row.
// b = bid&7 keeps each batch's 2.56MB z slab affine to one XCD L2.
// ---------------------------------------------------------------------------
__global__ __launch_bounds__(256) void out_kernel(
    const unsigned short* __restrict__ h_t, const unsigned short* __restrict__ z_t,
    const int* __restrict__ e0, const unsigned short* __restrict__ W2b,
    const float* __restrict__ b2, float* __restrict__ out)
{
  const int bid = blockIdx.x;
  const int b   = bid & 7;
  const int n0  = (bid >> 3) * 64;
  const int t   = threadIdx.x;
  const int lane = t & 63, w = t >> 6;
  const int lm = lane & 15, q = lane >> 4;

  __shared__ __align__(16) unsigned short cat[64 * 256];  // 32 KB, swizzled
  char* catB = (char*)cat;

  // ---- phase A: stage h + gather-max; thread = (nl = t>>2, c = t&3)
  {
    const int nl = t >> 2, c = t & 3;
    int gn = n0 + nl; if (gn >= NODES) gn = NODES - 1;

    // neighbor indices (quad-uniform addresses -> broadcast)
    const int* ep = e0 + ((size_t)b * NODES + gn) * KNB;
    uint4 iv0 = *(const uint4*)(ep);
    uint4 iv1 = *(const uint4*)(ep + 4);
    uint4 iv2 = *(const uint4*)(ep + 8);
    uint4 iv3 = *(const uint4*)(ep + 12);
    unsigned jns[KNB] = {iv0.x, iv0.y, iv0.z, iv0.w, iv1.x, iv1.y, iv1.z, iv1.w,
                         iv2.x, iv2.y, iv2.z, iv2.w, iv3.x, iv3.y, iv3.z, iv3.w};

    // h row: quad covers contiguous 64B (chunks 4j+c)
    const unsigned short* H = h_t + ((size_t)b * NODES + gn) * CH;
#pragma unroll
    for (int j = 0; j < 4; ++j) {
      const int ch = 4 * j + c;
      uint4 hv = *(const uint4*)(H + ch * 8);
      *(uint4*)(catB + nl * 512 + ((ch ^ (nl & 7)) << 4)) = hv;
    }

    // gather-max: per chunk, 16 batched loads then pkmax tree
    const unsigned short* Zb = z_t + (size_t)b * NODES * CH;
#pragma unroll
    for (int cg = 0; cg < 4; ++cg) {
      const int ch = cg * 4 + c;
      uint4 v[KNB];
#pragma unroll
      for (int k = 0; k < KNB; ++k)
        v[k] = *(const uint4*)(Zb + (size_t)jns[k] * CH + ch * 8);
#pragma unroll
      for (int k = 0; k < 8; ++k) v[k] = pkmax4(v[k], v[k + 8]);
#pragma unroll
      for (int k = 0; k < 4; ++k) v[k] = pkmax4(v[k], v[k + 4]);
      v[0] = pkmax4(v[0], v[2]);
      v[1] = pkmax4(v[1], v[3]);
      v[0] = pkmax4(v[0], v[1]);
      *(uint4*)(catB + nl * 512 + (((16 + ch) ^ (nl & 7)) << 4)) = v[0];
    }
  }

  __syncthreads();

  // ---- phase B: wave w -> d in [64w, 64w+64), 64 nodes, K=256, W2 prefetch
  const int d0 = w * 64;
  f32x4 acc[4][4];
#pragma unroll
  for (int dt = 0; dt < 4; ++dt)
#pragma unroll
    for (int nt = 0; nt < 4; ++nt) acc[dt][nt] = (f32x4){0.f, 0.f, 0.f, 0.f};

  uint4 acur[4], anxt[4];
#pragma unroll
  for (int dt = 0; dt < 4; ++dt)
    acur[dt] = *(const uint4*)(W2b + (size_t)(d0 + dt * 16 + lm) * CO + q * 8);

#pragma unroll
  for (int kt = 0; kt < 8; ++kt) {
    if (kt < 7) {
#pragma unroll
      for (int dt = 0; dt < 4; ++dt)
        anxt[dt] = *(const uint4*)(W2b + (size_t)(d0 + dt * 16 + lm) * CO
                                   + (kt + 1) * 32 + q * 8);
    }
#pragma unroll
    for (int nt = 0; nt < 4; ++nt) {
      const int nl = nt * 16 + lm;
      const int chunk = kt * 4 + q;
      bf16x8 bb = asbf8(*(const uint4*)(catB + nl * 512 + ((chunk ^ (nl & 7)) << 4)));
#pragma unroll
      for (int dt = 0; dt < 4; ++dt)
        acc[dt][nt] = __builtin_amdgcn_mfma_f32_16x16x32_bf16(
            asbf8(acur[dt]), bb, acc[dt][nt], 0, 0, 0);
    }
#pragma unroll
    for (int dt = 0; dt < 4; ++dt) acur[dt] = anxt[dt];
  }

  // ---- epilogue: fp32 out [b][d][n]
#pragma unroll
  for (int dt = 0; dt < 4; ++dt) {
    const int dbase = d0 + dt * 16 + q * 4;
    float4 bi = *(const float4*)(b2 + dbase);
    float bv[4] = {bi.x, bi.y, bi.z, bi.w};
#pragma unroll
    for (int nt = 0; nt < 4; ++nt) {
      const int gn = n0 + nt * 16 + lm;
      if (gn < NODES) {
        float* op = out + (size_t)(b * CO + dbase) * NODES + gn;
#pragma unroll
        for (int r = 0; r < 4; ++r)
          op[(size_t)r * NODES] = fmaxf(acc[dt][nt][r] + bv[r], 0.f);
      }
    }
  }
}

// ---------------------------------------------------------------------------
extern "C" void kernel_launch(void* const* d_in, const int* in_sizes, int n_in,
                              void* d_out, int out_size, void* d_ws, size_t ws_size,
                              hipStream_t stream) {
  const float* x  = (const float*)d_in[0];
  const int*   ei = (const int*)d_in[1];   // (2,B,N,K); first half = targets
  const float* W1 = (const float*)d_in[2];
  const float* b1 = (const float*)d_in[3];
  const float* Wp = (const float*)d_in[4];
  const float* bp = (const float*)d_in[5];
  const float* W2 = (const float*)d_in[6];
  const float* b2 = (const float*)d_in[7];
  float* out = (float*)d_out;

  unsigned short* ws  = (unsigned short*)d_ws;
  unsigned short* h_t = ws;                                   // [B][N][128] bf16
  unsigned short* z_t = h_t + (size_t)BATCH * NODES * CH;     // [B][N][128] bf16
  unsigned short* W1b = z_t + (size_t)BATCH * NODES * CH;
  unsigned short* Wpb = W1b + CH * CH;
  unsigned short* W2b = Wpb + CH * CH;

  prep<<<96, 256, 0, stream>>>(W1, Wp, W2, W1b, Wpb, W2b);

  const int NTF = (NODES + 127) / 128;  // 79
  fused_hz<<<dim3(NTF, BATCH), 256, 0, stream>>>(W1b, b1, Wpb, bp, x, h_t, z_t);

  const int NTO = (NODES + 63) / 64;    // 157
  out_kernel<<<BATCH * NTO, 256, 0, stream>>>(h_t, z_t, ei, W2b, b2, out);
}